// Round 20
// baseline (205.185 us; speedup 1.0000x reference)
//
#include <hip/hip_runtime.h>
#include <cstdint>
#include <cstddef>

#define N_NODES 100000
#define N_EDGES 600000
#define F_IN    128
#define HID     256
#define NC      64
#define NB_SCAN 391            // ceil(N_NODES/256)

typedef __attribute__((ext_vector_type(8))) short bf16x8;
typedef __attribute__((ext_vector_type(4))) float f32x4;

// fp32 -> bf16 round-to-nearest-even
__device__ __forceinline__ unsigned short f2bf(float f) {
    unsigned int u = __float_as_uint(f);
    u = (u + 0x7FFFu + ((u >> 16) & 1u)) >> 16;
    return (unsigned short)u;
}
__device__ __forceinline__ float bf2f(unsigned short u) {
    return __uint_as_float(((unsigned int)u) << 16);
}

__device__ __forceinline__ int load_idx(const void* ei, int m, long long i) {
    return m ? (int)((const long long*)ei)[i] : ((const int*)ei)[i];
}

// ---------------- degree histogram -----------------------------------------
__global__ void k_hist(const void* __restrict__ ei, const int* __restrict__ mode,
                       int* __restrict__ deg) {
    int e = blockIdx.x * blockDim.x + threadIdx.x;
    if (e >= N_EDGES) return;
    int d = load_idx(ei, *mode, (long long)N_EDGES + e);
    atomicAdd(&deg[d], 1);
}

// ---------------- CSR row_ptr: 3-step block scan ---------------------------
__global__ void k_scanA(const int* __restrict__ deg, int* __restrict__ ptmp,
                        int* __restrict__ bsum) {
    __shared__ int sm[256];
    int i = blockIdx.x * 256 + threadIdx.x;
    int v = (i < N_NODES) ? deg[i] : 0;
    sm[threadIdx.x] = v;
    __syncthreads();
    for (int off = 1; off < 256; off <<= 1) {
        int t = (threadIdx.x >= off) ? sm[threadIdx.x - off] : 0;
        __syncthreads();
        sm[threadIdx.x] += t;
        __syncthreads();
    }
    if (i < N_NODES) ptmp[i] = sm[threadIdx.x] - v;     // exclusive within block
    if (threadIdx.x == 255) bsum[blockIdx.x] = sm[255];
}

__global__ void k_scanB(int* __restrict__ bsum) {       // exclusive scan, NB<=512
    __shared__ int sm[512];
    int i = threadIdx.x;
    int v = (i < NB_SCAN) ? bsum[i] : 0;
    sm[i] = v;
    __syncthreads();
    for (int off = 1; off < 512; off <<= 1) {
        int t = (i >= off) ? sm[i - off] : 0;
        __syncthreads();
        sm[i] += t;
        __syncthreads();
    }
    if (i < NB_SCAN) bsum[i] = sm[i] - v;
}

__global__ void k_scanC(const int* __restrict__ deg, const int* __restrict__ ptmp,
                        const int* __restrict__ bsum, int* __restrict__ row_ptr,
                        int* __restrict__ cursor, float* __restrict__ dinv) {
    int i = blockIdx.x * 256 + threadIdx.x;
    if (i < N_NODES) {
        int rp = ptmp[i] + bsum[blockIdx.x];
        row_ptr[i] = rp;
        cursor[i]  = rp;
        dinv[i]    = rsqrtf(1.0f + (float)deg[i]);      // self-loop degree
    }
    if (i == 0) row_ptr[N_NODES] = N_EDGES;
}

// ---------------- CSR fill (order nondeterministic; fp-tolerant) -----------
__global__ void k_fill(const void* __restrict__ ei, const int* __restrict__ mode,
                       int* __restrict__ cursor, int* __restrict__ csr_src) {
    int e = blockIdx.x * blockDim.x + threadIdx.x;
    if (e >= N_EDGES) return;
    int m = *mode;
    int s = load_idx(ei, m, e);
    int d = load_idx(ei, m, (long long)N_EDGES + e);
    int pos = atomicAdd(&cursor[d], 1);
    csr_src[pos] = s;
}

// ---------------- fused prep: xbf + W1T + W2T + zero(deg) + detect ---------
#define XB_BLOCKS (N_NODES * F_IN / 8 / 256)    // 6250
#define W1_BLOCKS (F_IN * HID / 256)            // 128
#define W2_BLOCKS (HID * NC / 256)              // 64
#define PREP_BLOCKS (XB_BLOCKS + W1_BLOCKS + W2_BLOCKS)
__global__ void k_prep(const float* __restrict__ x, const float* __restrict__ W1,
                       const float* __restrict__ W2, unsigned short* __restrict__ xbf,
                       unsigned short* __restrict__ W1T, unsigned short* __restrict__ W2T,
                       int* __restrict__ deg, const int* __restrict__ ei_words,
                       int* __restrict__ mode) {
    int bid = blockIdx.x;
    int tid = threadIdx.x;
    if (bid < XB_BLOCKS) {
        int i = bid * 256 + tid;
        const float4* xr = (const float4*)x;
        float4 a = xr[(size_t)i * 2];
        float4 b = xr[(size_t)i * 2 + 1];
        bf16x8 o;
        o[0] = (short)f2bf(a.x); o[1] = (short)f2bf(a.y);
        o[2] = (short)f2bf(a.z); o[3] = (short)f2bf(a.w);
        o[4] = (short)f2bf(b.x); o[5] = (short)f2bf(b.y);
        o[6] = (short)f2bf(b.z); o[7] = (short)f2bf(b.w);
        *(bf16x8*)(xbf + (size_t)i * 8) = o;
    } else if (bid < XB_BLOCKS + W1_BLOCKS) {
        int i = (bid - XB_BLOCKS) * 256 + tid;
        int k = i >> 8, n = i & 255;
        W1T[n * F_IN + k] = f2bf(W1[i]);
    } else if (bid < PREP_BLOCKS) {
        int i = (bid - XB_BLOCKS - W1_BLOCKS) * 256 + tid;
        int k = i >> 6, n = i & 63;
        W2T[n * HID + k] = f2bf(W2[i]);
    } else if (bid < PREP_BLOCKS + NB_SCAN) {
        int i = (bid - PREP_BLOCKS) * 256 + tid;
        if (i < N_NODES) deg[i] = 0;
    } else {
        if (tid == 0) {
            int allz = 1;
            for (int i = 0; i < 64; ++i) {
                long long s = (long long)i * (N_EDGES - 1) / 63;
                if (ei_words[2 * s + 1] != 0) { allz = 0; break; }
            }
            *mode = allz;   // 1 => int64, 0 => int32
        }
    }
}

// ---------------- fused: px-gather + gemm1 + relu + gemm2, bf16 out --------
// 64-row blocks, 512 threads (8 waves), grid 1563 (tail-guarded):
//  phase 0: gather px rows via CSR (8 lanes/row x 16 feats) -> swizzled LDS
//  phase A: 8 waves x (32r x 64c) from LDS A-frags + L2 W1T -> bias/relu -> hlds
//  phase B: 8 waves x (16r x 32c) from hlds + L2 W2T -> hx2 (bf16)
// LDS 48 KB -> 3 blocks/CU (24 waves, 75%). Swizzle: byte ^= ((row&7)<<4).
__global__ __launch_bounds__(512) void k_mlp_fused(
        const unsigned short* __restrict__ xbf, const int* __restrict__ row_ptr,
        const int* __restrict__ csr_src, const float* __restrict__ dinv,
        const unsigned short* __restrict__ W1T, const float* __restrict__ b1,
        const unsigned short* __restrict__ W2T, unsigned short* __restrict__ hx2) {
    __shared__ unsigned short px_lds[64 * F_IN];        // 16 KB
    __shared__ unsigned short hlds[64 * HID];           // 32 KB
    const int lane = threadIdx.x & 63;
    const int w    = threadIdx.x >> 6;                  // 8 waves
    const int l15  = lane & 15, lhi = lane >> 4;
    const int row0 = blockIdx.x * 64;

    // ---- phase 0: gather this block's 64 px rows into px_lds ----
    {
        const int r   = threadIdx.x >> 3;               // 0..63 block-local row
        const int seg = threadIdx.x & 7;                // 16-feat segment
        const int n   = row0 + r;
        if (n < N_NODES) {
            const float dn = dinv[n];
            float acc16[16];
            const unsigned short* xp = xbf + (size_t)n * F_IN + seg * 16;
            bf16x8 v0 = *(const bf16x8*)(xp);
            bf16x8 v1 = *(const bf16x8*)(xp + 8);
#pragma unroll
            for (int t = 0; t < 8; ++t) {
                acc16[t]     = bf2f((unsigned short)v0[t]) * dn;
                acc16[8 + t] = bf2f((unsigned short)v1[t]) * dn;
            }
            int e0 = row_ptr[n], e1 = row_ptr[n + 1];
            for (int k = e0; k < e1; ++k) {
                int s = csr_src[k];                     // shared by 8 lanes of row
                float wv = dinv[s];
                const unsigned short* sp = xbf + (size_t)s * F_IN + seg * 16;
                bf16x8 u0 = *(const bf16x8*)(sp);
                bf16x8 u1 = *(const bf16x8*)(sp + 8);
#pragma unroll
                for (int t = 0; t < 8; ++t) {
                    acc16[t]     = fmaf(bf2f((unsigned short)u0[t]), wv, acc16[t]);
                    acc16[8 + t] = fmaf(bf2f((unsigned short)u1[t]), wv, acc16[8 + t]);
                }
            }
            bf16x8 w0, w1;
#pragma unroll
            for (int t = 0; t < 8; ++t) {
                w0[t] = (short)f2bf(acc16[t] * dn);
                w1[t] = (short)f2bf(acc16[8 + t] * dn);
            }
            unsigned base = (unsigned)(r * 256 + seg * 32);
            unsigned sw   = (unsigned)((r & 7) << 4);
            *(bf16x8*)((char*)px_lds + ((base) ^ sw))      = w0;
            *(bf16x8*)((char*)px_lds + ((base + 16) ^ sw)) = w1;
        }
    }
    __syncthreads();

    // ---- phase A: wave w -> rows (w>>2)*32..+31, cols (w&3)*64..+63 ----
    {
        const int rl0  = (w >> 2) * 32;
        const int col0 = (w & 3) * 64;
        bf16x8 a[4][2];                                 // A-frags from LDS
#pragma unroll
        for (int ks = 0; ks < 4; ++ks)
#pragma unroll
            for (int mt = 0; mt < 2; ++mt) {
                const int lr = rl0 + mt * 16 + l15;
                unsigned byte = (unsigned)(lr * 256 + ks * 64 + lhi * 16)
                              ^ (unsigned)((lr & 7) << 4);
                a[ks][mt] = *(const bf16x8*)((const char*)px_lds + byte);
            }

        f32x4 acc[2][4];
#pragma unroll
        for (int mt = 0; mt < 2; ++mt)
#pragma unroll
            for (int nt = 0; nt < 4; ++nt) acc[mt][nt] = (f32x4){0.f, 0.f, 0.f, 0.f};

#pragma unroll
        for (int ks = 0; ks < 4; ++ks) {
#pragma unroll
            for (int nt = 0; nt < 4; ++nt) {
                bf16x8 b = *(const bf16x8*)(W1T + (size_t)(col0 + nt * 16 + l15) * F_IN + ks * 32 + lhi * 8);
#pragma unroll
                for (int mt = 0; mt < 2; ++mt)
                    acc[mt][nt] = __builtin_amdgcn_mfma_f32_16x16x32_bf16(b, a[ks][mt], acc[mt][nt], 0, 0, 0);
            }
        }

        // epilogue: bias + relu -> bf16 -> swizzled hlds
#pragma unroll
        for (int mt = 0; mt < 2; ++mt) {
            const int lr = rl0 + mt * 16 + l15;         // block-local row
#pragma unroll
            for (int nt = 0; nt < 4; ++nt) {
                int c0 = col0 + nt * 16 + lhi * 4;
                float4 bb = *(const float4*)(b1 + c0);
                ushort4 o;
                o.x = f2bf(fmaxf(acc[mt][nt][0] + bb.x, 0.f));
                o.y = f2bf(fmaxf(acc[mt][nt][1] + bb.y, 0.f));
                o.z = f2bf(fmaxf(acc[mt][nt][2] + bb.z, 0.f));
                o.w = f2bf(fmaxf(acc[mt][nt][3] + bb.w, 0.f));
                unsigned byte = (unsigned)(lr * (HID * 2) + c0 * 2) ^ ((lr & 7) << 4);
                *(ushort4*)((char*)hlds + byte) = o;
            }
        }
    }
    __syncthreads();

    // ---- phase B: wave w -> rows (w>>1)*16..+15, cols (w&1)*32..+31 ----
    {
        const int lr = (w >> 1) * 16 + l15;             // block-local row
        const int cb = (w & 1) * 32;
        bf16x8 a2[8];
#pragma unroll
        for (int ks = 0; ks < 8; ++ks) {
            unsigned byte = (unsigned)(lr * (HID * 2) + ks * 64 + lhi * 16) ^ ((lr & 7) << 4);
            a2[ks] = *(const bf16x8*)((const char*)hlds + byte);
        }
        f32x4 acc2[2];
#pragma unroll
        for (int nt = 0; nt < 2; ++nt) acc2[nt] = (f32x4){0.f, 0.f, 0.f, 0.f};
#pragma unroll
        for (int nt = 0; nt < 2; ++nt) {
            const unsigned short* pb = W2T + (size_t)(cb + nt * 16 + l15) * HID + lhi * 8;
#pragma unroll
            for (int ks = 0; ks < 8; ++ks) {
                bf16x8 b = *(const bf16x8*)(pb + ks * 32);
                acc2[nt] = __builtin_amdgcn_mfma_f32_16x16x32_bf16(b, a2[ks], acc2[nt], 0, 0, 0);
            }
        }
        const int r = row0 + lr;
        if (r < N_NODES) {
#pragma unroll
            for (int nt = 0; nt < 2; ++nt) {
                int c0 = cb + nt * 16 + lhi * 4;
                ushort4 o;
                o.x = f2bf(acc2[nt][0]); o.y = f2bf(acc2[nt][1]);
                o.z = f2bf(acc2[nt][2]); o.w = f2bf(acc2[nt][3]);
                *(ushort4*)(hx2 + (size_t)r * NC + c0) = o;
            }
        }
    }
}

// ---------------- layer-2 propagation + bias + log_softmax -----------------
// hx2 is bf16 [N][64]; accumulate fp32, 1-deep prefetch on the edge loop.
__global__ void k_gather2sm(const unsigned short* __restrict__ hx2,
                            const int* __restrict__ row_ptr,
                            const int* __restrict__ csr_src, const float* __restrict__ dinv,
                            const float* __restrict__ b2, float* __restrict__ out) {
    int g = threadIdx.x >> 4;        // 16 nodes / block
    int j = threadIdx.x & 15;        // 16 lanes * 4 = 64 classes
    int n = blockIdx.x * 16 + g;
    float dn = dinv[n];
    ushort4 sv = *(const ushort4*)(hx2 + (size_t)n * NC + j * 4);
    float ax = bf2f(sv.x) * dn, ay = bf2f(sv.y) * dn,
          az = bf2f(sv.z) * dn, aw = bf2f(sv.w) * dn;
    int e0 = row_ptr[n], e1 = row_ptr[n + 1];
    float wvN = 0.f; ushort4 vN;
    if (e0 < e1) {
        int s0 = csr_src[e0];
        wvN = dinv[s0];
        vN = *(const ushort4*)(hx2 + (size_t)s0 * NC + j * 4);
    }
    for (int k = e0; k < e1; ++k) {
        float wv = wvN; ushort4 v = vN;
        if (k + 1 < e1) {
            int s2 = csr_src[k + 1];
            wvN = dinv[s2];
            vN = *(const ushort4*)(hx2 + (size_t)s2 * NC + j * 4);
        }
        ax = fmaf(bf2f(v.x), wv, ax); ay = fmaf(bf2f(v.y), wv, ay);
        az = fmaf(bf2f(v.z), wv, az); aw = fmaf(bf2f(v.w), wv, aw);
    }
    const float4 b = ((const float4*)b2)[j];
    float4 o;
    o.x = fmaf(ax, dn, b.x); o.y = fmaf(ay, dn, b.y);
    o.z = fmaf(az, dn, b.z); o.w = fmaf(aw, dn, b.w);
    float mx = fmaxf(fmaxf(o.x, o.y), fmaxf(o.z, o.w));
#pragma unroll
    for (int msk = 8; msk; msk >>= 1) mx = fmaxf(mx, __shfl_xor(mx, msk));
    float s4 = expf(o.x - mx) + expf(o.y - mx) + expf(o.z - mx) + expf(o.w - mx);
#pragma unroll
    for (int msk = 8; msk; msk >>= 1) s4 += __shfl_xor(s4, msk);
    float ls = mx + logf(s4);
    o.x -= ls; o.y -= ls; o.z -= ls; o.w -= ls;
    ((float4*)out)[(size_t)n * 16 + j] = o;
}

// ---------------- launch ----------------------------------------------------
extern "C" void kernel_launch(void* const* d_in, const int* in_sizes, int n_in,
                              void* d_out, int out_size, void* d_ws, size_t ws_size,
                              hipStream_t stream) {
    const float* x  = (const float*)d_in[0];
    const float* W1 = (const float*)d_in[1];
    const float* b1 = (const float*)d_in[2];
    const float* W2 = (const float*)d_in[3];
    const float* b2 = (const float*)d_in[4];
    const void*  ei = d_in[5];
    float* out = (float*)d_out;

    char* ws = (char*)d_ws;
    size_t off = 0;
    auto alloc = [&](size_t bytes) {
        char* p = ws + off;
        off += (bytes + 255) & ~(size_t)255;
        return p;
    };
    int*            mode    = (int*)            alloc(4);
    int*            deg     = (int*)            alloc((size_t)N_NODES * 4);
    int*            ptmp    = (int*)            alloc((size_t)N_NODES * 4);
    int*            bsum    = (int*)            alloc(4096);
    int*            row_ptr = (int*)            alloc((size_t)(N_NODES + 1) * 4);
    int*            cursor  = (int*)            alloc((size_t)N_NODES * 4);
    float*          dinv    = (float*)          alloc((size_t)N_NODES * 4);
    int*            csr_src = (int*)            alloc((size_t)N_EDGES * 4);
    unsigned short* W1T     = (unsigned short*) alloc((size_t)F_IN * HID * 2);
    unsigned short* W2T     = (unsigned short*) alloc((size_t)HID * NC * 2);
    unsigned short* xbf     = (unsigned short*) alloc((size_t)N_NODES * F_IN * 2);
    unsigned short* hx2     = (unsigned short*) alloc((size_t)(N_NODES + 64) * NC * 2);

    // merged prep: xbf + W1T + W2T + zero(deg) + dtype detect (one launch)
    k_prep<<<PREP_BLOCKS + NB_SCAN + 1, 256, 0, stream>>>(x, W1, W2, xbf, W1T, W2T,
                                                          deg, (const int*)ei, mode);

    k_hist<<<(N_EDGES + 255) / 256, 256, 0, stream>>>(ei, mode, deg);
    k_scanA<<<NB_SCAN, 256, 0, stream>>>(deg, ptmp, bsum);
    k_scanB<<<1, 512, 0, stream>>>(bsum);
    k_scanC<<<NB_SCAN, 256, 0, stream>>>(deg, ptmp, bsum, row_ptr, cursor, dinv);
    k_fill<<<(N_EDGES + 255) / 256, 256, 0, stream>>>(ei, mode, cursor, csr_src);

    // fused gather1+MLP (64-row blocks), then layer-2 propagate + softmax
    k_mlp_fused<<<(N_NODES + 63) / 64, 512, 0, stream>>>(xbf, row_ptr, csr_src, dinv,
                                                         W1T, b1, W2T, hx2);
    k_gather2sm<<<N_NODES / 16, 256, 0, stream>>>(hx2, row_ptr, csr_src, dinv, b2, out);
}

// Round 21
// 192.551 us; speedup vs baseline: 1.0656x; 1.0656x over previous
//
#include <hip/hip_runtime.h>
#include <cstdint>
#include <cstddef>

#define N_NODES 100000
#define N_EDGES 600000
#define F_IN    128
#define HID     256
#define NC      64
#define NB_SCAN 391            // ceil(N_NODES/256)

typedef __attribute__((ext_vector_type(8))) short bf16x8;
typedef __attribute__((ext_vector_type(4))) float f32x4;

// fp32 -> bf16 round-to-nearest-even
__device__ __forceinline__ unsigned short f2bf(float f) {
    unsigned int u = __float_as_uint(f);
    u = (u + 0x7FFFu + ((u >> 16) & 1u)) >> 16;
    return (unsigned short)u;
}
__device__ __forceinline__ float bf2f(unsigned short u) {
    return __uint_as_float(((unsigned int)u) << 16);
}

__device__ __forceinline__ int load_idx(const void* ei, int m, long long i) {
    return m ? (int)((const long long*)ei)[i] : ((const int*)ei)[i];
}

// ---------------- degree histogram -----------------------------------------
__global__ void k_hist(const void* __restrict__ ei, const int* __restrict__ mode,
                       int* __restrict__ deg) {
    int e = blockIdx.x * blockDim.x + threadIdx.x;
    if (e >= N_EDGES) return;
    int d = load_idx(ei, *mode, (long long)N_EDGES + e);
    atomicAdd(&deg[d], 1);
}

// ---------------- CSR row_ptr: 3-step block scan ---------------------------
__global__ void k_scanA(const int* __restrict__ deg, int* __restrict__ ptmp,
                        int* __restrict__ bsum) {
    __shared__ int sm[256];
    int i = blockIdx.x * 256 + threadIdx.x;
    int v = (i < N_NODES) ? deg[i] : 0;
    sm[threadIdx.x] = v;
    __syncthreads();
    for (int off = 1; off < 256; off <<= 1) {
        int t = (threadIdx.x >= off) ? sm[threadIdx.x - off] : 0;
        __syncthreads();
        sm[threadIdx.x] += t;
        __syncthreads();
    }
    if (i < N_NODES) ptmp[i] = sm[threadIdx.x] - v;     // exclusive within block
    if (threadIdx.x == 255) bsum[blockIdx.x] = sm[255];
}

__global__ void k_scanB(int* __restrict__ bsum) {       // exclusive scan, NB<=512
    __shared__ int sm[512];
    int i = threadIdx.x;
    int v = (i < NB_SCAN) ? bsum[i] : 0;
    sm[i] = v;
    __syncthreads();
    for (int off = 1; off < 512; off <<= 1) {
        int t = (i >= off) ? sm[i - off] : 0;
        __syncthreads();
        sm[i] += t;
        __syncthreads();
    }
    if (i < NB_SCAN) bsum[i] = sm[i] - v;
}

__global__ void k_scanC(const int* __restrict__ deg, const int* __restrict__ ptmp,
                        const int* __restrict__ bsum, int* __restrict__ row_ptr,
                        int* __restrict__ cursor, float* __restrict__ dinv) {
    int i = blockIdx.x * 256 + threadIdx.x;
    if (i < N_NODES) {
        int rp = ptmp[i] + bsum[blockIdx.x];
        row_ptr[i] = rp;
        cursor[i]  = rp;
        dinv[i]    = rsqrtf(1.0f + (float)deg[i]);      // self-loop degree
    }
    if (i == 0) row_ptr[N_NODES] = N_EDGES;
}

// ---------------- CSR fill (order nondeterministic; fp-tolerant) -----------
__global__ void k_fill(const void* __restrict__ ei, const int* __restrict__ mode,
                       int* __restrict__ cursor, int* __restrict__ csr_src) {
    int e = blockIdx.x * blockDim.x + threadIdx.x;
    if (e >= N_EDGES) return;
    int m = *mode;
    int s = load_idx(ei, m, e);
    int d = load_idx(ei, m, (long long)N_EDGES + e);
    int pos = atomicAdd(&cursor[d], 1);
    csr_src[pos] = s;
}

// ---------------- fused prep: xbf + W1T + W2T + zero(deg) + detect ---------
#define XB_BLOCKS (N_NODES * F_IN / 8 / 256)    // 6250
#define W1_BLOCKS (F_IN * HID / 256)            // 128
#define W2_BLOCKS (HID * NC / 256)              // 64
#define PREP_BLOCKS (XB_BLOCKS + W1_BLOCKS + W2_BLOCKS)
__global__ void k_prep(const float* __restrict__ x, const float* __restrict__ W1,
                       const float* __restrict__ W2, unsigned short* __restrict__ xbf,
                       unsigned short* __restrict__ W1T, unsigned short* __restrict__ W2T,
                       int* __restrict__ deg, const int* __restrict__ ei_words,
                       int* __restrict__ mode) {
    int bid = blockIdx.x;
    int tid = threadIdx.x;
    if (bid < XB_BLOCKS) {
        int i = bid * 256 + tid;
        const float4* xr = (const float4*)x;
        float4 a = xr[(size_t)i * 2];
        float4 b = xr[(size_t)i * 2 + 1];
        bf16x8 o;
        o[0] = (short)f2bf(a.x); o[1] = (short)f2bf(a.y);
        o[2] = (short)f2bf(a.z); o[3] = (short)f2bf(a.w);
        o[4] = (short)f2bf(b.x); o[5] = (short)f2bf(b.y);
        o[6] = (short)f2bf(b.z); o[7] = (short)f2bf(b.w);
        *(bf16x8*)(xbf + (size_t)i * 8) = o;
    } else if (bid < XB_BLOCKS + W1_BLOCKS) {
        int i = (bid - XB_BLOCKS) * 256 + tid;
        int k = i >> 8, n = i & 255;
        W1T[n * F_IN + k] = f2bf(W1[i]);
    } else if (bid < PREP_BLOCKS) {
        int i = (bid - XB_BLOCKS - W1_BLOCKS) * 256 + tid;
        int k = i >> 6, n = i & 63;
        W2T[n * HID + k] = f2bf(W2[i]);
    } else if (bid < PREP_BLOCKS + NB_SCAN) {
        int i = (bid - PREP_BLOCKS) * 256 + tid;
        if (i < N_NODES) deg[i] = 0;
    } else {
        if (tid == 0) {
            int allz = 1;
            for (int i = 0; i < 64; ++i) {
                long long s = (long long)i * (N_EDGES - 1) / 63;
                if (ei_words[2 * s + 1] != 0) { allz = 0; break; }
            }
            *mode = allz;   // 1 => int64, 0 => int32
        }
    }
}

// ---------------- fused: px-gather + gemm1 + relu + gemm2, bf16 out --------
// Per 32-row block (grid 3125 exact):
//  phase 0: gather px rows via CSR (8 lanes/row x 16 feats, 1-deep prefetch)
//  phase A: wave tile 32r x 64c from LDS A-frags + L2 W1T -> bias/relu -> hlds
//  phase B: wave tile 16r x 32c from hlds + L2 W2T -> hx2 (bf16)
// Swizzle involution everywhere: byte ^= ((row&7)<<4).
__global__ __launch_bounds__(256) void k_mlp_fused(
        const unsigned short* __restrict__ xbf, const int* __restrict__ row_ptr,
        const int* __restrict__ csr_src, const float* __restrict__ dinv,
        const unsigned short* __restrict__ W1T, const float* __restrict__ b1,
        const unsigned short* __restrict__ W2T, unsigned short* __restrict__ hx2) {
    __shared__ unsigned short px_lds[32 * F_IN];        // 8 KB
    __shared__ unsigned short hlds[32 * HID];           // 16 KB
    const int lane = threadIdx.x & 63;
    const int w    = threadIdx.x >> 6;                  // 4 waves
    const int l15  = lane & 15, lhi = lane >> 4;
    const int row0 = blockIdx.x * 32;

    // ---- phase 0: gather this block's 32 px rows into px_lds ----
    {
        const int r   = threadIdx.x >> 3;               // 0..31 block-local row
        const int seg = threadIdx.x & 7;                // 16-feat segment
        const int n   = row0 + r;
        const float dn = dinv[n];
        float acc16[16];
        const unsigned short* xp = xbf + (size_t)n * F_IN + seg * 16;
        bf16x8 v0 = *(const bf16x8*)(xp);
        bf16x8 v1 = *(const bf16x8*)(xp + 8);
#pragma unroll
        for (int t = 0; t < 8; ++t) {
            acc16[t]     = bf2f((unsigned short)v0[t]) * dn;
            acc16[8 + t] = bf2f((unsigned short)v1[t]) * dn;
        }
        int e0 = row_ptr[n], e1 = row_ptr[n + 1];
        // 1-deep software pipeline: prefetch next edge's index+weight+row
        float wvN = 0.f; bf16x8 u0N, u1N;
        if (e0 < e1) {
            int s0 = csr_src[e0];
            wvN = dinv[s0];
            const unsigned short* sp = xbf + (size_t)s0 * F_IN + seg * 16;
            u0N = *(const bf16x8*)(sp);
            u1N = *(const bf16x8*)(sp + 8);
        }
        for (int k = e0; k < e1; ++k) {
            float wv = wvN; bf16x8 u0 = u0N, u1 = u1N;
            if (k + 1 < e1) {
                int s2 = csr_src[k + 1];
                wvN = dinv[s2];
                const unsigned short* sp = xbf + (size_t)s2 * F_IN + seg * 16;
                u0N = *(const bf16x8*)(sp);
                u1N = *(const bf16x8*)(sp + 8);
            }
#pragma unroll
            for (int t = 0; t < 8; ++t) {
                acc16[t]     = fmaf(bf2f((unsigned short)u0[t]), wv, acc16[t]);
                acc16[8 + t] = fmaf(bf2f((unsigned short)u1[t]), wv, acc16[8 + t]);
            }
        }
        bf16x8 w0, w1;
#pragma unroll
        for (int t = 0; t < 8; ++t) {
            w0[t] = (short)f2bf(acc16[t] * dn);
            w1[t] = (short)f2bf(acc16[8 + t] * dn);
        }
        unsigned base = (unsigned)(r * 256 + seg * 32);
        unsigned sw   = (unsigned)((r & 7) << 4);
        *(bf16x8*)((char*)px_lds + ((base) ^ sw))      = w0;
        *(bf16x8*)((char*)px_lds + ((base + 16) ^ sw)) = w1;
    }
    __syncthreads();

    // ---- phase A: rows row0..row0+31, wave w -> cols w*64..w*64+63 ----
    {
        const int col0 = w * 64;
        bf16x8 a[4][2];                                 // A-frags from LDS
#pragma unroll
        for (int ks = 0; ks < 4; ++ks)
#pragma unroll
            for (int mt = 0; mt < 2; ++mt) {
                unsigned byte = (unsigned)((mt * 16 + l15) * 256 + ks * 64 + lhi * 16)
                              ^ (unsigned)((l15 & 7) << 4);
                a[ks][mt] = *(const bf16x8*)((const char*)px_lds + byte);
            }

        f32x4 acc[2][4];
#pragma unroll
        for (int mt = 0; mt < 2; ++mt)
#pragma unroll
            for (int nt = 0; nt < 4; ++nt) acc[mt][nt] = (f32x4){0.f, 0.f, 0.f, 0.f};

#pragma unroll
        for (int ks = 0; ks < 4; ++ks) {
#pragma unroll
            for (int nt = 0; nt < 4; ++nt) {
                bf16x8 b = *(const bf16x8*)(W1T + (size_t)(col0 + nt * 16 + l15) * F_IN + ks * 32 + lhi * 8);
#pragma unroll
                for (int mt = 0; mt < 2; ++mt)
                    acc[mt][nt] = __builtin_amdgcn_mfma_f32_16x16x32_bf16(b, a[ks][mt], acc[mt][nt], 0, 0, 0);
            }
        }

        // epilogue: bias + relu -> bf16 -> swizzled hlds
#pragma unroll
        for (int mt = 0; mt < 2; ++mt) {
            const int lr = mt * 16 + l15;               // block-local row
#pragma unroll
            for (int nt = 0; nt < 4; ++nt) {
                int c0 = col0 + nt * 16 + lhi * 4;
                float4 bb = *(const float4*)(b1 + c0);
                ushort4 o;
                o.x = f2bf(fmaxf(acc[mt][nt][0] + bb.x, 0.f));
                o.y = f2bf(fmaxf(acc[mt][nt][1] + bb.y, 0.f));
                o.z = f2bf(fmaxf(acc[mt][nt][2] + bb.z, 0.f));
                o.w = f2bf(fmaxf(acc[mt][nt][3] + bb.w, 0.f));
                unsigned byte = (unsigned)(lr * (HID * 2) + c0 * 2) ^ ((lr & 7) << 4);
                *(ushort4*)((char*)hlds + byte) = o;
            }
        }
    }
    __syncthreads();

    // ---- phase B: wave w -> rows (w&1)*16.., cols (w>>1)*32.. ----
    {
        const int lr = (w & 1) * 16 + l15;              // block-local row
        const int cb = (w >> 1) * 32;
        bf16x8 a2[8];
#pragma unroll
        for (int ks = 0; ks < 8; ++ks) {
            unsigned byte = (unsigned)(lr * (HID * 2) + ks * 64 + lhi * 16) ^ ((lr & 7) << 4);
            a2[ks] = *(const bf16x8*)((const char*)hlds + byte);
        }
        f32x4 acc2[2];
#pragma unroll
        for (int nt = 0; nt < 2; ++nt) acc2[nt] = (f32x4){0.f, 0.f, 0.f, 0.f};
#pragma unroll
        for (int nt = 0; nt < 2; ++nt) {
            const unsigned short* pb = W2T + (size_t)(cb + nt * 16 + l15) * HID + lhi * 8;
#pragma unroll
            for (int ks = 0; ks < 8; ++ks) {
                bf16x8 b = *(const bf16x8*)(pb + ks * 32);
                acc2[nt] = __builtin_amdgcn_mfma_f32_16x16x32_bf16(b, a2[ks], acc2[nt], 0, 0, 0);
            }
        }
        const int r = row0 + lr;                        // grid exact: r < N_NODES
#pragma unroll
        for (int nt = 0; nt < 2; ++nt) {
            int c0 = cb + nt * 16 + lhi * 4;
            ushort4 o;
            o.x = f2bf(acc2[nt][0]); o.y = f2bf(acc2[nt][1]);
            o.z = f2bf(acc2[nt][2]); o.w = f2bf(acc2[nt][3]);
            *(ushort4*)(hx2 + (size_t)r * NC + c0) = o;
        }
    }
}

// ---------------- layer-2 propagation + bias + log_softmax -----------------
// hx2 is bf16 [N][64]; accumulate fp32, 1-deep prefetch on the edge loop.
__global__ void k_gather2sm(const unsigned short* __restrict__ hx2,
                            const int* __restrict__ row_ptr,
                            const int* __restrict__ csr_src, const float* __restrict__ dinv,
                            const float* __restrict__ b2, float* __restrict__ out) {
    int g = threadIdx.x >> 4;        // 16 nodes / block
    int j = threadIdx.x & 15;        // 16 lanes * 4 = 64 classes
    int n = blockIdx.x * 16 + g;
    float dn = dinv[n];
    ushort4 sv = *(const ushort4*)(hx2 + (size_t)n * NC + j * 4);
    float ax = bf2f(sv.x) * dn, ay = bf2f(sv.y) * dn,
          az = bf2f(sv.z) * dn, aw = bf2f(sv.w) * dn;
    int e0 = row_ptr[n], e1 = row_ptr[n + 1];
    float wvN = 0.f; ushort4 vN;
    if (e0 < e1) {
        int s0 = csr_src[e0];
        wvN = dinv[s0];
        vN = *(const ushort4*)(hx2 + (size_t)s0 * NC + j * 4);
    }
    for (int k = e0; k < e1; ++k) {
        float wv = wvN; ushort4 v = vN;
        if (k + 1 < e1) {
            int s2 = csr_src[k + 1];
            wvN = dinv[s2];
            vN = *(const ushort4*)(hx2 + (size_t)s2 * NC + j * 4);
        }
        ax = fmaf(bf2f(v.x), wv, ax); ay = fmaf(bf2f(v.y), wv, ay);
        az = fmaf(bf2f(v.z), wv, az); aw = fmaf(bf2f(v.w), wv, aw);
    }
    const float4 b = ((const float4*)b2)[j];
    float4 o;
    o.x = fmaf(ax, dn, b.x); o.y = fmaf(ay, dn, b.y);
    o.z = fmaf(az, dn, b.z); o.w = fmaf(aw, dn, b.w);
    float mx = fmaxf(fmaxf(o.x, o.y), fmaxf(o.z, o.w));
#pragma unroll
    for (int msk = 8; msk; msk >>= 1) mx = fmaxf(mx, __shfl_xor(mx, msk));
    float s4 = expf(o.x - mx) + expf(o.y - mx) + expf(o.z - mx) + expf(o.w - mx);
#pragma unroll
    for (int msk = 8; msk; msk >>= 1) s4 += __shfl_xor(s4, msk);
    float ls = mx + logf(s4);
    o.x -= ls; o.y -= ls; o.z -= ls; o.w -= ls;
    ((float4*)out)[(size_t)n * 16 + j] = o;
}

// ---------------- launch ----------------------------------------------------
extern "C" void kernel_launch(void* const* d_in, const int* in_sizes, int n_in,
                              void* d_out, int out_size, void* d_ws, size_t ws_size,
                              hipStream_t stream) {
    const float* x  = (const float*)d_in[0];
    const float* W1 = (const float*)d_in[1];
    const float* b1 = (const float*)d_in[2];
    const float* W2 = (const float*)d_in[3];
    const float* b2 = (const float*)d_in[4];
    const void*  ei = d_in[5];
    float* out = (float*)d_out;

    char* ws = (char*)d_ws;
    size_t off = 0;
    auto alloc = [&](size_t bytes) {
        char* p = ws + off;
        off += (bytes + 255) & ~(size_t)255;
        return p;
    };
    int*            mode    = (int*)            alloc(4);
    int*            deg     = (int*)            alloc((size_t)N_NODES * 4);
    int*            ptmp    = (int*)            alloc((size_t)N_NODES * 4);
    int*            bsum    = (int*)            alloc(4096);
    int*            row_ptr = (int*)            alloc((size_t)(N_NODES + 1) * 4);
    int*            cursor  = (int*)            alloc((size_t)N_NODES * 4);
    float*          dinv    = (float*)          alloc((size_t)N_NODES * 4);
    int*            csr_src = (int*)            alloc((size_t)N_EDGES * 4);
    unsigned short* W1T     = (unsigned short*) alloc((size_t)F_IN * HID * 2);
    unsigned short* W2T     = (unsigned short*) alloc((size_t)HID * NC * 2);
    unsigned short* xbf     = (unsigned short*) alloc((size_t)N_NODES * F_IN * 2);
    unsigned short* hx2     = (unsigned short*) alloc((size_t)(N_NODES + 64) * NC * 2);

    // merged prep: xbf + W1T + W2T + zero(deg) + dtype detect (one launch)
    k_prep<<<PREP_BLOCKS + NB_SCAN + 1, 256, 0, stream>>>(x, W1, W2, xbf, W1T, W2T,
                                                          deg, (const int*)ei, mode);

    k_hist<<<(N_EDGES + 255) / 256, 256, 0, stream>>>(ei, mode, deg);
    k_scanA<<<NB_SCAN, 256, 0, stream>>>(deg, ptmp, bsum);
    k_scanB<<<1, 512, 0, stream>>>(bsum);
    k_scanC<<<NB_SCAN, 256, 0, stream>>>(deg, ptmp, bsum, row_ptr, cursor, dinv);
    k_fill<<<(N_EDGES + 255) / 256, 256, 0, stream>>>(ei, mode, cursor, csr_src);

    // fused gather1+MLP, then layer-2 propagate + bias + log_softmax
    k_mlp_fused<<<N_NODES / 32, 256, 0, stream>>>(xbf, row_ptr, csr_src, dinv,
                                                  W1T, b1, W2T, hx2);
    k_gather2sm<<<N_NODES / 16, 256, 0, stream>>>(hx2, row_ptr, csr_src, dinv, b2, out);
}